// Round 6
// baseline (8556.818 us; speedup 1.0000x reference)
//
#include <hip/hip_runtime.h>
#include <hip/hip_bf16.h>
#include <hip/hip_cooperative_groups.h>

namespace cg = cooperative_groups;

typedef unsigned short ushort_t;
typedef unsigned int uint32;
typedef __attribute__((ext_vector_type(8))) __bf16 bf16x8;
typedef __attribute__((ext_vector_type(4))) float f32x4;
typedef __attribute__((ext_vector_type(4))) unsigned int u32x4;

#define SEQ_LEN 1024
#define NWG 64
#define NTHR 256

#define XPACK_BYTES (64ull << 20)                  /* 1024*16*64*4 units * 16B */
#define WPACK_BYTES (4ull << 20)                   /* 64 WG * 64KB  */
#define HB_OFF  (XPACK_BYTES + WPACK_BYTES)        /* tagged h double buffer, 256KB */
#define WS_NEED (HB_OFF + (256ull << 10))

__device__ __forceinline__ ushort_t f2bf(float f) {
  unsigned u = __builtin_bit_cast(unsigned, f);
  unsigned r = (u + 0x7fffu + ((u >> 16) & 1u)) >> 16;
  return (ushort_t)r;
}
__device__ __forceinline__ float sigm(float x) {
  float e = __expf(-x);
  return __builtin_amdgcn_rcpf(1.f + e);
}
__device__ __forceinline__ float tanh_fast(float x) {
  float a = fabsf(x);
  float e = __expf(-2.f * a);
  float r = (1.f - e) * __builtin_amdgcn_rcpf(1.f + e);
  return copysignf(r, x);
}
__device__ __forceinline__ uint32 umin2(uint32 a, uint32 b) { return a < b ? a : b; }

__global__ void zero_mem_kernel(u32x4* p) {
  int i = blockIdx.x * blockDim.x + threadIdx.x;
  u32x4 z = {0u, 0u, 0u, 0u};
  p[i] = z;
}

// pack x (f32 -> bf16, frag-major): unit (t,kk,b,hi) holds x[b][t][32kk+8hi+r], r=0..7
__global__ void pack_x_kernel(const float* __restrict__ x, u32x4* __restrict__ xp) {
  unsigned u = blockIdx.x * blockDim.x + threadIdx.x;
  int hi = u & 3;
  int kk = (u >> 2) & 15;
  int t  = (u >> 6) & 1023;
  int b  = u >> 16;
  const float* src = x + (((size_t)b * SEQ_LEN + t) * 512 + (kk << 5) + (hi << 3));
  f32x4 f0 = *(const f32x4*)(src);
  f32x4 f1 = *(const f32x4*)(src + 4);
  u32x4 o;
  o[0] = f2bf(f0[0]) | ((uint32)f2bf(f0[1]) << 16);
  o[1] = f2bf(f0[2]) | ((uint32)f2bf(f0[3]) << 16);
  o[2] = f2bf(f1[0]) | ((uint32)f2bf(f1[1]) << 16);
  o[3] = f2bf(f1[2]) | ((uint32)f2bf(f1[3]) << 16);
  xp[(size_t)((t * 16 + kk) * 64 + b) * 4 + hi] = o;
}

// pack W = [W_i; W_h] per-WG frag-major: col = gate*512 + wg*8 + tau*4 + hcl,
// lane = 16*hi + (hcl<<2|gate), k = 32kk+8hi+r, dst [wg][kk(0..31)][tau][lane][r]
__global__ void pack_w_kernel(const float* __restrict__ Wi, const float* __restrict__ Wh,
                              ushort_t* __restrict__ wp) {
  unsigned e = blockIdx.x * blockDim.x + threadIdx.x;  // 1024*2048
  int k = e >> 11;
  int col = e & 2047;
  float v = (k < 512) ? Wi[(size_t)k * 2048 + col] : Wh[(size_t)(k - 512) * 2048 + col];
  int wg  = (col & 511) >> 3;
  int tau = (col >> 2) & 1;
  int hcl = col & 3;
  int gate = col >> 9;
  int p = (hcl << 2) | gate;
  int kk = k >> 5;
  int hi = (k >> 3) & 3;
  int r = k & 7;
  int lane = (hi << 4) | p;
  wp[(size_t)wg * 32768 + (size_t)(((kk * 2) + tau) * 64 + lane) * 8 + r] = f2bf(v);
}

// persistent LSTM. Per WG: 8 h-cols (2 MFMA tiles of 16 gate-cols each).
// D layout: col = lane&15 (batch), row = 4*(lane>>4)+reg = (hcl<<2|gate)
// => each lane owns h-cols kh0 = wg*8+(lane>>4), kh1 = kh0+4, gates = regs.
// FAST sync: h stored as u32 = (tag << 16) | bf16(h). Producers fire-and-forget;
// consumers poll-load the tagged data and check min(words) >= t<<16.
// FAST is a PLAIN launch (no grid.sync anywhere in it); slow path is cooperative.
template<bool FAST>
__global__ void __launch_bounds__(NTHR, 1)
lstm_coop(const float* __restrict__ x, const float* __restrict__ Wi,
          const float* __restrict__ Wh, const float* __restrict__ bias,
          const u32x4* __restrict__ xpack, const u32x4* __restrict__ wpack,
          uint32* hbuf32, ushort_t* hbuf16, float* out)
{
  __shared__ u32x4 lA[4096];   // 64KB: [kk 0..31][tau 0..1][lane 0..63] 16B frags
  const int tid  = threadIdx.x;
  const int wg   = blockIdx.x;
  const int lane = tid & 63;
  const int wv   = tid >> 6;
  const int hi2  = lane >> 4;
  const int lo   = lane & 15;
  const int b    = (wv << 4) | lo;

  if constexpr (FAST) {
    const u32x4* wsrc = wpack + (size_t)wg * 2048 * 2;   // 4096 units per WG
    for (int i = tid; i < 4096; i += NTHR) lA[i] = wsrc[i];
  } else {
    for (int uu = tid; uu < 4096; uu += NTHR) {
      int ln = uu & 63, tau = (uu >> 6) & 1, kk = uu >> 7;
      int uhi = ln >> 4, p = ln & 15;
      int gate = p & 3, hcl = p >> 2;
      int col = gate * 512 + (wg << 3) + tau * 4 + hcl;
      ushort_t tmp[8];
#pragma unroll
      for (int r = 0; r < 8; ++r) {
        int k = (kk << 5) + (uhi << 3) + r;
        float f = (k < 512) ? Wi[(size_t)k * 2048 + col] : Wh[(size_t)(k - 512) * 2048 + col];
        tmp[r] = f2bf(f);
      }
      u32x4 v;
      v[0] = tmp[0] | ((uint32)tmp[1] << 16);
      v[1] = tmp[2] | ((uint32)tmp[3] << 16);
      v[2] = tmp[4] | ((uint32)tmp[5] << 16);
      v[3] = tmp[6] | ((uint32)tmp[7] << 16);
      lA[uu] = v;
    }
  }
  __syncthreads();

  const int kh0 = (wg << 3) | hi2;
  const int kh1 = kh0 + 4;
  const float b00 = bias[0 * 512 + kh0], b01 = bias[1 * 512 + kh0];
  const float b02 = bias[2 * 512 + kh0], b03 = bias[3 * 512 + kh0];
  const float b10 = bias[0 * 512 + kh1], b11 = bias[1 * 512 + kh1];
  const float b12 = bias[2 * 512 + kh1], b13 = bias[3 * 512 + kh1];

  // element offset (u32 units in FAST, u16 units in slow) within one slot
  const int hoff0 = (((kh0 >> 5) * 256 + b * 4 + ((kh0 >> 3) & 3)) << 3) + (kh0 & 7);
  const int hoff1 = hoff0 + 4;

  // recurrent-weight fragments (compiler-managed)
  bf16x8 whA[16], whB[16];
#pragma unroll
  for (int kk = 0; kk < 16; ++kk) {
    whA[kk] = __builtin_bit_cast(bf16x8, lA[((16 + kk) * 2 + 0) * 64 + lane]);
    whB[kk] = __builtin_bit_cast(bf16x8, lA[((16 + kk) * 2 + 1) * 64 + lane]);
  }

  float c0 = 0.f, c1 = 0.f, hn0 = 0.f, hn1 = 0.f;

  for (int t = 0; t < SEQ_LEN; ++t) {
    // ---- x-projection part (independent of h; hides h-store propagation) ----
    f32x4 ax0 = {b00, b01, b02, b03};
    f32x4 ax1 = {b10, b11, b12, b13};
    if constexpr (FAST) {
      const u32x4* xb = xpack + (size_t)t * 4096 + b * 4 + hi2;
#pragma unroll
      for (int kk = 0; kk < 16; ++kk) {
        bf16x8 xv = __builtin_bit_cast(bf16x8, xb[kk * 256]);
        bf16x8 a0 = __builtin_bit_cast(bf16x8, lA[(kk * 2 + 0) * 64 + lane]);
        bf16x8 a1 = __builtin_bit_cast(bf16x8, lA[(kk * 2 + 1) * 64 + lane]);
        ax0 = __builtin_amdgcn_mfma_f32_16x16x32_bf16(a0, xv, ax0, 0, 0, 0);
        ax1 = __builtin_amdgcn_mfma_f32_16x16x32_bf16(a1, xv, ax1, 0, 0, 0);
      }
    } else {
      const float* xr = x + ((size_t)b * SEQ_LEN + t) * 512 + (hi2 << 3);
#pragma unroll
      for (int kk = 0; kk < 16; ++kk) {
        f32x4 f0 = *(const f32x4*)(xr + (kk << 5));
        f32x4 f1 = *(const f32x4*)(xr + (kk << 5) + 4);
        u32x4 v;
        v[0] = f2bf(f0[0]) | ((uint32)f2bf(f0[1]) << 16);
        v[1] = f2bf(f0[2]) | ((uint32)f2bf(f0[3]) << 16);
        v[2] = f2bf(f1[0]) | ((uint32)f2bf(f1[1]) << 16);
        v[3] = f2bf(f1[2]) | ((uint32)f2bf(f1[3]) << 16);
        bf16x8 xv = __builtin_bit_cast(bf16x8, v);
        bf16x8 a0 = __builtin_bit_cast(bf16x8, lA[(kk * 2 + 0) * 64 + lane]);
        bf16x8 a1 = __builtin_bit_cast(bf16x8, lA[(kk * 2 + 1) * 64 + lane]);
        ax0 = __builtin_amdgcn_mfma_f32_16x16x32_bf16(a0, xv, ax0, 0, 0, 0);
        ax1 = __builtin_amdgcn_mfma_f32_16x16x32_bf16(a1, xv, ax1, 0, 0, 0);
      }
    }

    f32x4 ah0 = {0.f, 0.f, 0.f, 0.f};
    f32x4 ah1 = {0.f, 0.f, 0.f, 0.f};

    if constexpr (FAST) {
      // ---- poll-load tagged h_t: detection and data load are the same op ----
      const u32x4* hr = (const u32x4*)hbuf32 + (size_t)(t & 1) * 8192
                        + ((size_t)b * 4 + hi2) * 2;
      const uint32 thr = (uint32)t << 16;
      u32x4 hreg[32];
      while (true) {
#pragma unroll
        for (int kk = 0; kk < 16; ++kk) {
          asm volatile("global_load_dwordx4 %0, %1, off sc0 sc1"
                       : "=v"(hreg[2 * kk]) : "v"(hr + kk * 512) : "memory");
          asm volatile("global_load_dwordx4 %0, %1, off sc0 sc1"
                       : "=v"(hreg[2 * kk + 1]) : "v"(hr + kk * 512 + 1) : "memory");
        }
        asm volatile("s_waitcnt vmcnt(0)" ::: "memory");
        __builtin_amdgcn_sched_barrier(0);
        uint32 mn = 0xFFFFFFFFu;
#pragma unroll
        for (int i = 0; i < 32; ++i) {
          u32x4 v = hreg[i];
          mn = umin2(mn, umin2(umin2(v[0], v[1]), umin2(v[2], v[3])));
        }
        if (__all(mn >= thr)) break;
      }
      // ---- strip tags: pack low halves to bf16 frags (shift/mask) ----
#pragma unroll
      for (int kk = 0; kk < 16; ++kk) {
        u32x4 lo4 = hreg[2 * kk], hi4 = hreg[2 * kk + 1];
        u32x4 p;
        p[0] = (lo4[0] & 0xFFFFu) | (lo4[1] << 16);
        p[1] = (lo4[2] & 0xFFFFu) | (lo4[3] << 16);
        p[2] = (hi4[0] & 0xFFFFu) | (hi4[1] << 16);
        p[3] = (hi4[2] & 0xFFFFu) | (hi4[3] << 16);
        bf16x8 hv = __builtin_bit_cast(bf16x8, p);
        ah0 = __builtin_amdgcn_mfma_f32_16x16x32_bf16(whA[kk], hv, ah0, 0, 0, 0);
        ah1 = __builtin_amdgcn_mfma_f32_16x16x32_bf16(whB[kk], hv, ah1, 0, 0, 0);
      }
    } else {
      const u32x4* hr = (const u32x4*)hbuf16 + (size_t)(t & 1) * 4096 + b * 4 + hi2;
#pragma unroll
      for (int kk = 0; kk < 16; ++kk) {
        bf16x8 hv = __builtin_bit_cast(bf16x8, hr[kk * 256]);
        ah0 = __builtin_amdgcn_mfma_f32_16x16x32_bf16(whA[kk], hv, ah0, 0, 0, 0);
        ah1 = __builtin_amdgcn_mfma_f32_16x16x32_bf16(whB[kk], hv, ah1, 0, 0, 0);
      }
    }

    // ---- cell update (2 cells per lane) ----
    {
      float gi = ax0[0] + ah0[0], gf = ax0[1] + ah0[1];
      float gg = ax0[2] + ah0[2], go = ax0[3] + ah0[3];
      float it = sigm(gi), ft = sigm(gf), ot = sigm(go), gt = tanh_fast(gg);
      c0 = ft * c0 + it * gt;
      hn0 = ot * tanh_fast(c0);
    }
    {
      float gi = ax1[0] + ah1[0], gf = ax1[1] + ah1[1];
      float gg = ax1[2] + ah1[2], go = ax1[3] + ah1[3];
      float it = sigm(gi), ft = sigm(gf), ot = sigm(go), gt = tanh_fast(gg);
      c1 = ft * c1 + it * gt;
      hn1 = ot * tanh_fast(c1);
    }

    if (t < SEQ_LEN - 1) {
      if constexpr (FAST) {
        uint32* hw = hbuf32 + (size_t)((t + 1) & 1) * 32768;
        uint32 tag = (uint32)(t + 1) << 16;
        uint32 w0 = tag | f2bf(hn0);
        uint32 w1 = tag | f2bf(hn1);
        // fire-and-forget: no drain, no flag, no syncthreads
        asm volatile("global_store_dword %0, %1, off sc0 sc1"
                     :: "v"(hw + hoff0), "v"(w0) : "memory");
        asm volatile("global_store_dword %0, %1, off sc0 sc1"
                     :: "v"(hw + hoff1), "v"(w1) : "memory");
      } else {
        ushort_t* hw = hbuf16 + (size_t)((t + 1) & 1) * 32768;
        hw[hoff0] = f2bf(hn0);
        hw[hoff1] = f2bf(hn1);
        __threadfence();
        cg::this_grid().sync();
        __threadfence();
      }
    } else {
      if constexpr (!FAST) {
        __threadfence();
        cg::this_grid().sync();   // d_out aliases hbuf in slow path
      }
    }
  }

  out[(size_t)b * 512 + kh0] = hn0;
  out[(size_t)b * 512 + kh1] = hn1;
  out[32768 + (size_t)b * 512 + kh0] = c0;
  out[32768 + (size_t)b * 512 + kh1] = c1;
}

extern "C" void kernel_launch(void* const* d_in, const int* in_sizes, int n_in,
                              void* d_out, int out_size, void* d_ws, size_t ws_size,
                              hipStream_t stream) {
  const float* x    = (const float*)d_in[0];
  const float* Wi   = (const float*)d_in[1];
  const float* Wh   = (const float*)d_in[2];
  const float* bias = (const float*)d_in[3];
  float* out = (float*)d_out;

  bool fast = (d_ws != nullptr) && (ws_size >= WS_NEED);

  if (fast) {
    const u32x4* xpack = (const u32x4*)d_ws;
    const u32x4* wpack = (const u32x4*)((char*)d_ws + XPACK_BYTES);
    uint32* hbuf32 = (uint32*)((char*)d_ws + HB_OFF);
    ushort_t* hbuf16 = (ushort_t*)d_out;  // unused on fast path

    zero_mem_kernel<<<64, 256, 0, stream>>>((u32x4*)((char*)d_ws + HB_OFF)); // 256KB tagged hbuf
    pack_x_kernel<<<16384, 256, 0, stream>>>(x, (u32x4*)d_ws);
    pack_w_kernel<<<8192, 256, 0, stream>>>(Wi, Wh, (ushort_t*)((char*)d_ws + XPACK_BYTES));

    // FAST path needs no grid.sync -> plain launch (64 WGs co-resident on 256 CUs)
    lstm_coop<true><<<dim3(NWG), dim3(NTHR), 0, stream>>>(
        x, Wi, Wh, bias, xpack, wpack, hbuf32, hbuf16, out);
  } else {
    uint32* hbuf32 = (uint32*)d_out;      // unused on slow path
    ushort_t* hbuf16 = (ushort_t*)d_out;  // h double-buffer inside d_out
    const u32x4* xpack = (const u32x4*)x;
    const u32x4* wpack = (const u32x4*)Wi;

    zero_mem_kernel<<<16, 256, 0, stream>>>((u32x4*)d_out);  // 64KB slot0

    void* args[] = {(void*)&x, (void*)&Wi, (void*)&Wh, (void*)&bias,
                    (void*)&xpack, (void*)&wpack, (void*)&hbuf32, (void*)&hbuf16, (void*)&out};
    void (*kfn)(const float*, const float*, const float*, const float*,
                const u32x4*, const u32x4*, uint32*, ushort_t*, float*) = lstm_coop<false>;
    hipLaunchCooperativeKernel(reinterpret_cast<void*>(kfn), dim3(NWG), dim3(NTHR),
                               args, 0, stream);
  }
}

// Round 7
// 7106.550 us; speedup vs baseline: 1.2041x; 1.2041x over previous
//
#include <hip/hip_runtime.h>
#include <hip/hip_bf16.h>
#include <hip/hip_cooperative_groups.h>

namespace cg = cooperative_groups;

typedef unsigned short ushort_t;
typedef unsigned int uint32;
typedef __attribute__((ext_vector_type(8))) __bf16 bf16x8;
typedef __attribute__((ext_vector_type(4))) float f32x4;
typedef __attribute__((ext_vector_type(4))) unsigned int u32x4;

#define SEQ_LEN 1024
#define NWG 64
#define NTHR 256

#define XPACK_BYTES (64ull << 20)                  /* 1024*16*64*4 units * 16B */
#define WPACK_BYTES (4ull << 20)                   /* 64 WG * 64KB  */
#define HB_OFF  (XPACK_BYTES + WPACK_BYTES)        /* tagged h double buffer, 256KB */
#define FLG_OFF (HB_OFF + (256ull << 10))          /* 256 per-wave flags, 1KB (zeroed 4KB) */
#define WS_NEED (FLG_OFF + (4ull << 10))

__device__ __forceinline__ ushort_t f2bf(float f) {
  unsigned u = __builtin_bit_cast(unsigned, f);
  unsigned r = (u + 0x7fffu + ((u >> 16) & 1u)) >> 16;
  return (ushort_t)r;
}
__device__ __forceinline__ float sigm(float x) {
  float e = __expf(-x);
  return __builtin_amdgcn_rcpf(1.f + e);
}
__device__ __forceinline__ float tanh_fast(float x) {
  float a = fabsf(x);
  float e = __expf(-2.f * a);
  float r = (1.f - e) * __builtin_amdgcn_rcpf(1.f + e);
  return copysignf(r, x);
}
__device__ __forceinline__ uint32 umin2(uint32 a, uint32 b) { return a < b ? a : b; }

__global__ void zero_mem_kernel(u32x4* p) {
  int i = blockIdx.x * blockDim.x + threadIdx.x;
  u32x4 z = {0u, 0u, 0u, 0u};
  p[i] = z;
}

// pack x (f32 -> bf16, frag-major): unit (t,kk,b,hi) holds x[b][t][32kk+8hi+r], r=0..7
__global__ void pack_x_kernel(const float* __restrict__ x, u32x4* __restrict__ xp) {
  unsigned u = blockIdx.x * blockDim.x + threadIdx.x;
  int hi = u & 3;
  int kk = (u >> 2) & 15;
  int t  = (u >> 6) & 1023;
  int b  = u >> 16;
  const float* src = x + (((size_t)b * SEQ_LEN + t) * 512 + (kk << 5) + (hi << 3));
  f32x4 f0 = *(const f32x4*)(src);
  f32x4 f1 = *(const f32x4*)(src + 4);
  u32x4 o;
  o[0] = f2bf(f0[0]) | ((uint32)f2bf(f0[1]) << 16);
  o[1] = f2bf(f0[2]) | ((uint32)f2bf(f0[3]) << 16);
  o[2] = f2bf(f1[0]) | ((uint32)f2bf(f1[1]) << 16);
  o[3] = f2bf(f1[2]) | ((uint32)f2bf(f1[3]) << 16);
  xp[(size_t)((t * 16 + kk) * 64 + b) * 4 + hi] = o;
}

// pack W = [W_i; W_h] per-WG frag-major: col = gate*512 + wg*8 + tau*4 + hcl,
// lane = 16*hi + (hcl<<2|gate), k = 32kk+8hi+r, dst [wg][kk(0..31)][tau][lane][r]
__global__ void pack_w_kernel(const float* __restrict__ Wi, const float* __restrict__ Wh,
                              ushort_t* __restrict__ wp) {
  unsigned e = blockIdx.x * blockDim.x + threadIdx.x;  // 1024*2048
  int k = e >> 11;
  int col = e & 2047;
  float v = (k < 512) ? Wi[(size_t)k * 2048 + col] : Wh[(size_t)(k - 512) * 2048 + col];
  int wg  = (col & 511) >> 3;
  int tau = (col >> 2) & 1;
  int hcl = col & 3;
  int gate = col >> 9;
  int p = (hcl << 2) | gate;
  int kk = k >> 5;
  int hi = (k >> 3) & 3;
  int r = k & 7;
  int lane = (hi << 4) | p;
  wp[(size_t)wg * 32768 + (size_t)(((kk * 2) + tau) * 64 + lane) * 8 + r] = f2bf(v);
}

// persistent LSTM. Per WG: 8 h-cols (2 MFMA tiles of 16 gate-cols each).
// D layout: col = lane&15 (batch), row = 4*(lane>>4)+reg = (hcl<<2|gate)
// => each lane owns h-cols kh0 = wg*8+(lane>>4), kh1 = kh0+4, gates = regs.
// FAST sync (hybrid):
//   producer: tagged h stores (u32 = (t+1)<<16 | bf16) fire-and-forget, then
//             per-wave flag store (ALSO un-drained; flag may overtake data).
//   consumer: cheap spin on 1KB flag array (16B/lane), then ONE bulk tagged
//             load validated by min-tree over tags; rare retry closes the
//             flag-overtook-data window. Tags are the correctness gate.
// FAST is a PLAIN launch; slow path is cooperative grid.sync.
template<bool FAST>
__global__ void __launch_bounds__(NTHR, 1)
lstm_coop(const float* __restrict__ x, const float* __restrict__ Wi,
          const float* __restrict__ Wh, const float* __restrict__ bias,
          const u32x4* __restrict__ xpack, const u32x4* __restrict__ wpack,
          uint32* hbuf32, ushort_t* hbuf16, uint32* flags, float* out)
{
  __shared__ u32x4 lA[4096];   // 64KB: [kk 0..31][tau 0..1][lane 0..63] 16B frags
  const int tid  = threadIdx.x;
  const int wg   = blockIdx.x;
  const int lane = tid & 63;
  const int wv   = tid >> 6;
  const int hi2  = lane >> 4;
  const int lo   = lane & 15;
  const int b    = (wv << 4) | lo;

  if constexpr (FAST) {
    const u32x4* wsrc = wpack + (size_t)wg * 2048 * 2;   // 4096 units per WG
    for (int i = tid; i < 4096; i += NTHR) lA[i] = wsrc[i];
  } else {
    for (int uu = tid; uu < 4096; uu += NTHR) {
      int ln = uu & 63, tau = (uu >> 6) & 1, kk = uu >> 7;
      int uhi = ln >> 4, p = ln & 15;
      int gate = p & 3, hcl = p >> 2;
      int col = gate * 512 + (wg << 3) + tau * 4 + hcl;
      ushort_t tmp[8];
#pragma unroll
      for (int r = 0; r < 8; ++r) {
        int k = (kk << 5) + (uhi << 3) + r;
        float f = (k < 512) ? Wi[(size_t)k * 2048 + col] : Wh[(size_t)(k - 512) * 2048 + col];
        tmp[r] = f2bf(f);
      }
      u32x4 v;
      v[0] = tmp[0] | ((uint32)tmp[1] << 16);
      v[1] = tmp[2] | ((uint32)tmp[3] << 16);
      v[2] = tmp[4] | ((uint32)tmp[5] << 16);
      v[3] = tmp[6] | ((uint32)tmp[7] << 16);
      lA[uu] = v;
    }
  }
  __syncthreads();

  const int kh0 = (wg << 3) | hi2;
  const int kh1 = kh0 + 4;
  const float b00 = bias[0 * 512 + kh0], b01 = bias[1 * 512 + kh0];
  const float b02 = bias[2 * 512 + kh0], b03 = bias[3 * 512 + kh0];
  const float b10 = bias[0 * 512 + kh1], b11 = bias[1 * 512 + kh1];
  const float b12 = bias[2 * 512 + kh1], b13 = bias[3 * 512 + kh1];

  // element offset (u32 units in FAST, u16 units in slow) within one slot
  const int hoff0 = (((kh0 >> 5) * 256 + b * 4 + ((kh0 >> 3) & 3)) << 3) + (kh0 & 7);
  const int hoff1 = hoff0 + 4;

  // recurrent-weight fragments (compiler-managed)
  bf16x8 whA[16], whB[16];
#pragma unroll
  for (int kk = 0; kk < 16; ++kk) {
    whA[kk] = __builtin_bit_cast(bf16x8, lA[((16 + kk) * 2 + 0) * 64 + lane]);
    whB[kk] = __builtin_bit_cast(bf16x8, lA[((16 + kk) * 2 + 1) * 64 + lane]);
  }

  float c0 = 0.f, c1 = 0.f, hn0 = 0.f, hn1 = 0.f;

  for (int t = 0; t < SEQ_LEN; ++t) {
    // ---- x-projection part (independent of h; hides h-store propagation) ----
    f32x4 ax0 = {b00, b01, b02, b03};
    f32x4 ax1 = {b10, b11, b12, b13};
    if constexpr (FAST) {
      const u32x4* xb = xpack + (size_t)t * 4096 + b * 4 + hi2;
#pragma unroll
      for (int kk = 0; kk < 16; ++kk) {
        bf16x8 xv = __builtin_bit_cast(bf16x8, xb[kk * 256]);
        bf16x8 a0 = __builtin_bit_cast(bf16x8, lA[(kk * 2 + 0) * 64 + lane]);
        bf16x8 a1 = __builtin_bit_cast(bf16x8, lA[(kk * 2 + 1) * 64 + lane]);
        ax0 = __builtin_amdgcn_mfma_f32_16x16x32_bf16(a0, xv, ax0, 0, 0, 0);
        ax1 = __builtin_amdgcn_mfma_f32_16x16x32_bf16(a1, xv, ax1, 0, 0, 0);
      }
    } else {
      const float* xr = x + ((size_t)b * SEQ_LEN + t) * 512 + (hi2 << 3);
#pragma unroll
      for (int kk = 0; kk < 16; ++kk) {
        f32x4 f0 = *(const f32x4*)(xr + (kk << 5));
        f32x4 f1 = *(const f32x4*)(xr + (kk << 5) + 4);
        u32x4 v;
        v[0] = f2bf(f0[0]) | ((uint32)f2bf(f0[1]) << 16);
        v[1] = f2bf(f0[2]) | ((uint32)f2bf(f0[3]) << 16);
        v[2] = f2bf(f1[0]) | ((uint32)f2bf(f1[1]) << 16);
        v[3] = f2bf(f1[2]) | ((uint32)f2bf(f1[3]) << 16);
        bf16x8 xv = __builtin_bit_cast(bf16x8, v);
        bf16x8 a0 = __builtin_bit_cast(bf16x8, lA[(kk * 2 + 0) * 64 + lane]);
        bf16x8 a1 = __builtin_bit_cast(bf16x8, lA[(kk * 2 + 1) * 64 + lane]);
        ax0 = __builtin_amdgcn_mfma_f32_16x16x32_bf16(a0, xv, ax0, 0, 0, 0);
        ax1 = __builtin_amdgcn_mfma_f32_16x16x32_bf16(a1, xv, ax1, 0, 0, 0);
      }
    }

    f32x4 ah0 = {0.f, 0.f, 0.f, 0.f};
    f32x4 ah1 = {0.f, 0.f, 0.f, 0.f};

    if constexpr (FAST) {
      // ---- cheap pacing poll: 256 per-wave flags, 16B per lane per iter ----
      if (t > 0) {
        const u32x4* fa = (const u32x4*)flags + lane;   // lane L -> WG L's 4 flags
        const uint32 tt = (uint32)t;
        while (true) {
          u32x4 v;
          asm volatile("global_load_dwordx4 %0, %1, off sc0 sc1\n\ts_waitcnt vmcnt(0)"
                       : "=v"(v) : "v"(fa) : "memory");
          bool ok = (v[0] >= tt) & (v[1] >= tt) & (v[2] >= tt) & (v[3] >= tt);
          if (__all(ok)) break;
        }
      }
      // ---- bulk tagged load; tags are the correctness gate (rare retry) ----
      const u32x4* hr = (const u32x4*)hbuf32 + (size_t)(t & 1) * 8192
                        + ((size_t)b * 4 + hi2) * 2;
      const uint32 thr = (uint32)t << 16;
      u32x4 hreg[32];
      while (true) {
#pragma unroll
        for (int kk = 0; kk < 16; ++kk) {
          asm volatile("global_load_dwordx4 %0, %1, off sc0 sc1"
                       : "=v"(hreg[2 * kk]) : "v"(hr + kk * 512) : "memory");
          asm volatile("global_load_dwordx4 %0, %1, off sc0 sc1"
                       : "=v"(hreg[2 * kk + 1]) : "v"(hr + kk * 512 + 1) : "memory");
        }
        asm volatile("s_waitcnt vmcnt(0)" ::: "memory");
        __builtin_amdgcn_sched_barrier(0);
        uint32 mn = 0xFFFFFFFFu;
#pragma unroll
        for (int i = 0; i < 32; ++i) {
          u32x4 v = hreg[i];
          mn = umin2(mn, umin2(umin2(v[0], v[1]), umin2(v[2], v[3])));
        }
        if (__all(mn >= thr)) break;
      }
      // ---- strip tags: pack low halves to bf16 frags (shift/mask) ----
#pragma unroll
      for (int kk = 0; kk < 16; ++kk) {
        u32x4 lo4 = hreg[2 * kk], hi4 = hreg[2 * kk + 1];
        u32x4 p;
        p[0] = (lo4[0] & 0xFFFFu) | (lo4[1] << 16);
        p[1] = (lo4[2] & 0xFFFFu) | (lo4[3] << 16);
        p[2] = (hi4[0] & 0xFFFFu) | (hi4[1] << 16);
        p[3] = (hi4[2] & 0xFFFFu) | (hi4[3] << 16);
        bf16x8 hv = __builtin_bit_cast(bf16x8, p);
        ah0 = __builtin_amdgcn_mfma_f32_16x16x32_bf16(whA[kk], hv, ah0, 0, 0, 0);
        ah1 = __builtin_amdgcn_mfma_f32_16x16x32_bf16(whB[kk], hv, ah1, 0, 0, 0);
      }
    } else {
      const u32x4* hr = (const u32x4*)hbuf16 + (size_t)(t & 1) * 4096 + b * 4 + hi2;
#pragma unroll
      for (int kk = 0; kk < 16; ++kk) {
        bf16x8 hv = __builtin_bit_cast(bf16x8, hr[kk * 256]);
        ah0 = __builtin_amdgcn_mfma_f32_16x16x32_bf16(whA[kk], hv, ah0, 0, 0, 0);
        ah1 = __builtin_amdgcn_mfma_f32_16x16x32_bf16(whB[kk], hv, ah1, 0, 0, 0);
      }
    }

    // ---- cell update (2 cells per lane) ----
    {
      float gi = ax0[0] + ah0[0], gf = ax0[1] + ah0[1];
      float gg = ax0[2] + ah0[2], go = ax0[3] + ah0[3];
      float it = sigm(gi), ft = sigm(gf), ot = sigm(go), gt = tanh_fast(gg);
      c0 = ft * c0 + it * gt;
      hn0 = ot * tanh_fast(c0);
    }
    {
      float gi = ax1[0] + ah1[0], gf = ax1[1] + ah1[1];
      float gg = ax1[2] + ah1[2], go = ax1[3] + ah1[3];
      float it = sigm(gi), ft = sigm(gf), ot = sigm(go), gt = tanh_fast(gg);
      c1 = ft * c1 + it * gt;
      hn1 = ot * tanh_fast(c1);
    }

    if (t < SEQ_LEN - 1) {
      if constexpr (FAST) {
        uint32* hw = hbuf32 + (size_t)((t + 1) & 1) * 32768;
        uint32 tag = (uint32)(t + 1) << 16;
        uint32 w0 = tag | f2bf(hn0);
        uint32 w1 = tag | f2bf(hn1);
        // fire-and-forget tagged data
        asm volatile("global_store_dword %0, %1, off sc0 sc1"
                     :: "v"(hw + hoff0), "v"(w0) : "memory");
        asm volatile("global_store_dword %0, %1, off sc0 sc1"
                     :: "v"(hw + hoff1), "v"(w1) : "memory");
        // un-drained pacing flag (may overtake data; tags cover that window)
        if (lane == 0) {
          uint32* fp = flags + (wg << 2) + wv;
          uint32 val = (uint32)(t + 1);
          asm volatile("global_store_dword %0, %1, off sc0 sc1"
                       :: "v"(fp), "v"(val) : "memory");
        }
      } else {
        ushort_t* hw = hbuf16 + (size_t)((t + 1) & 1) * 32768;
        hw[hoff0] = f2bf(hn0);
        hw[hoff1] = f2bf(hn1);
        __threadfence();
        cg::this_grid().sync();
        __threadfence();
      }
    } else {
      if constexpr (!FAST) {
        __threadfence();
        cg::this_grid().sync();   // d_out aliases hbuf in slow path
      }
    }
  }

  out[(size_t)b * 512 + kh0] = hn0;
  out[(size_t)b * 512 + kh1] = hn1;
  out[32768 + (size_t)b * 512 + kh0] = c0;
  out[32768 + (size_t)b * 512 + kh1] = c1;
}

extern "C" void kernel_launch(void* const* d_in, const int* in_sizes, int n_in,
                              void* d_out, int out_size, void* d_ws, size_t ws_size,
                              hipStream_t stream) {
  const float* x    = (const float*)d_in[0];
  const float* Wi   = (const float*)d_in[1];
  const float* Wh   = (const float*)d_in[2];
  const float* bias = (const float*)d_in[3];
  float* out = (float*)d_out;

  bool fast = (d_ws != nullptr) && (ws_size >= WS_NEED);

  if (fast) {
    const u32x4* xpack = (const u32x4*)d_ws;
    const u32x4* wpack = (const u32x4*)((char*)d_ws + XPACK_BYTES);
    uint32* hbuf32 = (uint32*)((char*)d_ws + HB_OFF);
    uint32* flags  = (uint32*)((char*)d_ws + FLG_OFF);
    ushort_t* hbuf16 = (ushort_t*)d_out;  // unused on fast path

    // zero 256KB tagged hbuf + 4KB flags region (65 blocks x 4KB)
    zero_mem_kernel<<<65, 256, 0, stream>>>((u32x4*)((char*)d_ws + HB_OFF));
    pack_x_kernel<<<16384, 256, 0, stream>>>(x, (u32x4*)d_ws);
    pack_w_kernel<<<8192, 256, 0, stream>>>(Wi, Wh, (ushort_t*)((char*)d_ws + XPACK_BYTES));

    // FAST path needs no grid.sync -> plain launch (64 WGs co-resident on 256 CUs)
    lstm_coop<true><<<dim3(NWG), dim3(NTHR), 0, stream>>>(
        x, Wi, Wh, bias, xpack, wpack, hbuf32, hbuf16, flags, out);
  } else {
    uint32* hbuf32 = (uint32*)d_out;      // unused on slow path
    ushort_t* hbuf16 = (ushort_t*)d_out;  // h double-buffer inside d_out
    uint32* flags = (uint32*)d_out;       // unused on slow path
    const u32x4* xpack = (const u32x4*)x;
    const u32x4* wpack = (const u32x4*)Wi;

    zero_mem_kernel<<<16, 256, 0, stream>>>((u32x4*)d_out);  // 64KB slot0

    void* args[] = {(void*)&x, (void*)&Wi, (void*)&Wh, (void*)&bias,
                    (void*)&xpack, (void*)&wpack, (void*)&hbuf32, (void*)&hbuf16,
                    (void*)&flags, (void*)&out};
    void (*kfn)(const float*, const float*, const float*, const float*,
                const u32x4*, const u32x4*, uint32*, ushort_t*, uint32*, float*) =
        lstm_coop<false>;
    hipLaunchCooperativeKernel(reinterpret_cast<void*>(kfn), dim3(NWG), dim3(NTHR),
                               args, 0, stream);
  }
}